// Round 1
// baseline (1332.344 us; speedup 1.0000x reference)
//
#include <hip/hip_runtime.h>
#include <math.h>

#define EPSC 1e-8f
#define TOPK 5
#define BM 128
#define BN 128
#define BK 16

__device__ __forceinline__ bool better(float va, int ia, float vb, int ib) {
    return (va > vb) || (va == vb && ia < ib);
}

// ---------------- center = mean(spatial_weights, axis=0) ----------------
__global__ void k_center(const float* __restrict__ sw, int H, float* __restrict__ center) {
    int tid = threadIdx.x;  // 64 threads
    float sx = 0.f, sy = 0.f;
    for (int r = tid; r < H; r += 64) { sx += sw[2 * r]; sy += sw[2 * r + 1]; }
    for (int o = 32; o > 0; o >>= 1) { sx += __shfl_down(sx, o); sy += __shfl_down(sy, o); }
    if (tid == 0) { center[0] = sx / (float)H; center[1] = sy / (float)H; }
}

// ---------------- qnT[d][b] = query[b][d] / max(||q_b||, eps) ----------------
__global__ void k_qnormT(const float* __restrict__ q, float* __restrict__ qnT, int B, int D) {
    int b = blockIdx.x;
    int tid = threadIdx.x;  // 128 threads
    float ss = 0.f;
    for (int d = tid; d < D; d += 128) { float v = q[(size_t)b * D + d]; ss += v * v; }
    for (int o = 32; o > 0; o >>= 1) ss += __shfl_down(ss, o);
    __shared__ float w2[2];
    if ((tid & 63) == 0) w2[tid >> 6] = ss;
    __syncthreads();
    float inv = 1.f / fmaxf(sqrtf(w2[0] + w2[1]), EPSC);
    for (int d = tid; d < D; d += 128) qnT[(size_t)d * B + b] = q[(size_t)b * D + d] * inv;
}

// ---------------- generic transpose src[R][C] -> dst[C][R] ----------------
__global__ void k_transpose(const float* __restrict__ src, float* __restrict__ dst, int R, int C) {
    __shared__ float tile[32][33];
    int bx = blockIdx.x, by = blockIdx.y;
    int x = bx * 32 + threadIdx.x;
    for (int i = threadIdx.y; i < 32; i += 8) {
        int y = by * 32 + i;
        if (y < R && x < C) tile[i][threadIdx.x] = src[(size_t)y * C + x];
    }
    __syncthreads();
    int xx = by * 32 + threadIdx.x;
    for (int i = threadIdx.y; i < 32; i += 8) {
        int c = bx * 32 + i;
        if (c < C && xx < R) dst[(size_t)c * R + xx] = tile[threadIdx.x][i];
    }
}

// ---------------- main: sim GEMM + fused mem-norm + act + per-tile top-5 ----------------
// grid: (ntiles, B/BM), 256 threads. Tile: BM=128 query rows x BN=128 memory cols.
__launch_bounds__(256, 4)
__global__ void k_sim_topk(const float* __restrict__ qnT, const float* __restrict__ mem,
                           const float* __restrict__ coords, const float* __restrict__ center,
                           float* __restrict__ candV, int* __restrict__ candI,
                           int M, int B, int D) {
    __shared__ float smem[8704];  // 34.8 KB
    float* As = smem;             // [BK][BM]
    float* Bs = smem + 2048;      // [BK][BN]

    const int tile = blockIdx.x, by = blockIdx.y;
    const int n0 = tile * BN, bm0 = by * BM;
    const int tid = threadIdx.x;
    const int tr = tid >> 4, tc = tid & 15;

    float acc[8][8];
#pragma unroll
    for (int i = 0; i < 8; ++i)
#pragma unroll
        for (int j = 0; j < 8; ++j) acc[i][j] = 0.f;

    float ssacc = 0.f;
    const int ssn = tid & 127, sshalf = tid >> 7;

    for (int kt = 0; kt < D; kt += BK) {
#pragma unroll
        for (int u = 0; u < 2; ++u) {  // A: qnT[k][m], already transposed
            int c = tid + u * 256;
            int k = c >> 5, m4 = (c & 31) << 2;
            float4 v = *(const float4*)&qnT[(size_t)(kt + k) * B + bm0 + m4];
            *(float4*)&As[k * BM + m4] = v;
        }
#pragma unroll
        for (int u = 0; u < 2; ++u) {  // B: mem row-major -> transpose on LDS store
            int c = tid + u * 256;
            int n = c >> 2, k4 = (c & 3) << 2;
            int m = n0 + n;
            float4 v = make_float4(0.f, 0.f, 0.f, 0.f);
            if (m < M) v = *(const float4*)&mem[(size_t)m * D + kt + k4];
            Bs[(k4 + 0) * BN + n] = v.x;
            Bs[(k4 + 1) * BN + n] = v.y;
            Bs[(k4 + 2) * BN + n] = v.z;
            Bs[(k4 + 3) * BN + n] = v.w;
        }
        __syncthreads();
        // fused memory-vector sum-of-squares (col ssn, k-half sshalf)
#pragma unroll
        for (int kk = 0; kk < 8; ++kk) {
            float bv = Bs[(sshalf * 8 + kk) * BN + ssn];
            ssacc = fmaf(bv, bv, ssacc);
        }
#pragma unroll
        for (int k = 0; k < BK; ++k) {
            float a[8], bb[8];
            *(float4*)&a[0] = *(float4*)&As[k * BM + tr * 8];
            *(float4*)&a[4] = *(float4*)&As[k * BM + tr * 8 + 4];
            *(float4*)&bb[0] = *(float4*)&Bs[k * BN + tc * 8];
            *(float4*)&bb[4] = *(float4*)&Bs[k * BN + tc * 8 + 4];
#pragma unroll
            for (int i = 0; i < 8; ++i)
#pragma unroll
                for (int j = 0; j < 8; ++j) acc[i][j] = fmaf(a[i], bb[j], acc[i][j]);
        }
        __syncthreads();
    }

    // column stats: inv_norm and activation bias
    float* ssbuf = smem + 8192;   // 256
    float* colinv = smem + 8448;  // 128
    float* colact = smem + 8576;  // 128
    ssbuf[tid] = ssacc;
    __syncthreads();
    if (tid < BN) {
        float ss = ssbuf[tid] + ssbuf[tid + 128];
        colinv[tid] = 1.f / fmaxf(sqrtf(ss), EPSC);
        int m = n0 + tid;
        float act;
        if (m < M) {
            float dx = coords[2 * (size_t)m] - center[0];
            float dy = coords[2 * (size_t)m + 1] - center[1];
            act = 1.f / (1.f + sqrtf(dx * dx + dy * dy));
        } else act = -INFINITY;
        colact[tid] = act;
    }
    __syncthreads();

    // two half-passes through a 128x64 LDS C tile; per-row top-5 in registers
    float* Cs = smem;  // 128*64, overlays As/Bs (dead)
    float lv[TOPK]; int li[TOPK];
#pragma unroll
    for (int k = 0; k < TOPK; ++k) { lv[k] = -INFINITY; li[k] = 0x7fffffff; }
    const int r = tid >> 1, s = tid & 1;

    for (int hf = 0; hf < 2; ++hf) {
        if ((tc >> 3) == hf) {
            int cbase = (tc & 7) * 8;
#pragma unroll
            for (int i = 0; i < 8; ++i) {
                int row = tr * 8 + i;
#pragma unroll
                for (int j = 0; j < 8; ++j) {
                    int c = cbase + j;
                    int cg = hf * 64 + c;
                    Cs[row * 64 + c] = fmaf(acc[i][j], colinv[cg], colact[cg]);
                }
            }
        }
        __syncthreads();
        for (int j = 0; j < 32; ++j) {
            int c = s * 32 + ((j + r) & 31);  // rotate start to avoid bank conflicts
            float v = Cs[r * 64 + c];
            int gi = n0 + hf * 64 + c;
            if (better(v, gi, lv[4], li[4])) {
                lv[4] = v; li[4] = gi;
#pragma unroll
                for (int p = 4; p > 0; --p) {
                    if (better(lv[p], li[p], lv[p - 1], li[p - 1])) {
                        float tv = lv[p]; lv[p] = lv[p - 1]; lv[p - 1] = tv;
                        int ti = li[p]; li[p] = li[p - 1]; li[p - 1] = ti;
                    }
                }
            }
        }
        __syncthreads();
    }

    // merge the (r, s=0) and (r, s=1) lists -> per-row top-5 candidates
    float* mv = smem;                 // 128*2*5
    int* mi = (int*)(smem + 1280);    // 128*2*5
#pragma unroll
    for (int k = 0; k < TOPK; ++k) { mv[(r * 2 + s) * TOPK + k] = lv[k]; mi[(r * 2 + s) * TOPK + k] = li[k]; }
    __syncthreads();
    if (s == 0) {
        float ov[TOPK]; int oi[TOPK];
        int pa = 0, pb = 0;
#pragma unroll
        for (int k = 0; k < TOPK; ++k) {
            float va = lv[pa]; int ia = li[pa];
            float vb = mv[(r * 2 + 1) * TOPK + pb]; int ib = mi[(r * 2 + 1) * TOPK + pb];
            if (better(va, ia, vb, ib)) { ov[k] = va; oi[k] = ia; ++pa; }
            else { ov[k] = vb; oi[k] = ib; ++pb; }
        }
        int gb = bm0 + r;
        size_t base = ((size_t)tile * B + gb) * TOPK;
#pragma unroll
        for (int k = 0; k < TOPK; ++k) { candV[base + k] = ov[k]; candI[base + k] = oi[k]; }
    }
}

// ---------------- merge per-tile candidates -> global top-5 (sorted desc) ----------------
__global__ void k_merge(const float* __restrict__ candV, const int* __restrict__ candI,
                        int ntiles, int B, int* __restrict__ topk) {
    int b = blockIdx.x;
    int tid = threadIdx.x;  // 256
    float lv[TOPK]; int li[TOPK];
#pragma unroll
    for (int k = 0; k < TOPK; ++k) { lv[k] = -INFINITY; li[k] = 0x7fffffff; }
    for (int t = tid; t < ntiles; t += 256) {
        size_t base = ((size_t)t * B + b) * TOPK;
#pragma unroll
        for (int k = 0; k < TOPK; ++k) {
            float v = candV[base + k]; int gi = candI[base + k];
            if (better(v, gi, lv[4], li[4])) {
                lv[4] = v; li[4] = gi;
#pragma unroll
                for (int p = 4; p > 0; --p) {
                    if (better(lv[p], li[p], lv[p - 1], li[p - 1])) {
                        float tv = lv[p]; lv[p] = lv[p - 1]; lv[p - 1] = tv;
                        int ti = li[p]; li[p] = li[p - 1]; li[p - 1] = ti;
                    }
                }
            }
        }
    }
    __shared__ float sv[256 * TOPK];
    __shared__ int si[256 * TOPK];
#pragma unroll
    for (int k = 0; k < TOPK; ++k) { sv[tid * TOPK + k] = lv[k]; si[tid * TOPK + k] = li[k]; }
    __syncthreads();
    __shared__ float rv[256];
    __shared__ int ri[256], rp[256];
    for (int round = 0; round < TOPK; ++round) {
        float bv = -INFINITY; int bi = 0x7fffffff, bp = -1;
        for (int p = tid; p < 256 * TOPK; p += 256) {
            if (better(sv[p], si[p], bv, bi)) { bv = sv[p]; bi = si[p]; bp = p; }
        }
        rv[tid] = bv; ri[tid] = bi; rp[tid] = bp;
        __syncthreads();
        for (int st = 128; st > 0; st >>= 1) {
            if (tid < st) {
                if (better(rv[tid + st], ri[tid + st], rv[tid], ri[tid])) {
                    rv[tid] = rv[tid + st]; ri[tid] = ri[tid + st]; rp[tid] = rp[tid + st];
                }
            }
            __syncthreads();
        }
        if (tid == 0) {
            topk[b * TOPK + round] = ri[0];
            sv[rp[0]] = -INFINITY;
            si[rp[0]] = 0x7fffffff;
        }
        __syncthreads();
    }
}

// ---------------- x_proj (6 timesteps) + gate, fused ----------------
__launch_bounds__(512)
__global__ void k_xproj(const float* __restrict__ q, const float* __restrict__ mem,
                        const int* __restrict__ topk,
                        const float* __restrict__ WihT, const float* __restrict__ gWT,
                        const float* __restrict__ b_ih, const float* __restrict__ gate_b,
                        float* __restrict__ xp, float* __restrict__ gate,
                        int B, int M, int D, int H) {
    int b = blockIdx.x;
    int tid = threadIdx.x;  // H threads
    __shared__ float inp[6 * 512];
    for (int c = tid; c < 6 * D; c += blockDim.x) {
        int t = c / D, d = c - t * D;
        const float* src = (t == 0) ? &q[(size_t)b * D] : &mem[(size_t)topk[b * TOPK + (t - 1)] * D];
        inp[t * D + d] = src[d];
    }
    __syncthreads();
    int h = tid;
    float a0 = 0.f, a1 = 0.f, a2 = 0.f, a3 = 0.f, a4 = 0.f, a5 = 0.f, g = 0.f;
    for (int d = 0; d < D; ++d) {
        float w = WihT[(size_t)d * H + h];
        float gw = gWT[(size_t)d * H + h];
        a0 = fmaf(inp[0 * D + d], w, a0);
        a1 = fmaf(inp[1 * D + d], w, a1);
        a2 = fmaf(inp[2 * D + d], w, a2);
        a3 = fmaf(inp[3 * D + d], w, a3);
        a4 = fmaf(inp[4 * D + d], w, a4);
        a5 = fmaf(inp[5 * D + d], w, a5);
        g = fmaf(inp[0 * D + d], gw, g);
    }
    float bb = b_ih[h];
    size_t xb = (size_t)b * 6 * H + h;
    xp[xb + 0 * H] = a0 + bb;
    xp[xb + 1 * H] = a1 + bb;
    xp[xb + 2 * H] = a2 + bb;
    xp[xb + 3 * H] = a3 + bb;
    xp[xb + 4 * H] = a4 + bb;
    xp[xb + 5 * H] = a5 + bb;
    gate[(size_t)b * H + h] = 1.f / (1.f + expf(-(g + gate_b[h])));
}

// ---------------- one RNN step (optionally final combine) ----------------
__launch_bounds__(512)
__global__ void k_rnn(const float* __restrict__ xp, const float* __restrict__ WhhT,
                      const float* __restrict__ b_hh, float* __restrict__ hbuf,
                      const float* __restrict__ gate, float* __restrict__ out,
                      int t, int H, int first, int last) {
    int b = blockIdx.x, h = threadIdx.x;
    __shared__ float hp[1024];
    if (!first) hp[h] = hbuf[(size_t)b * H + h];
    __syncthreads();
    float acc = xp[((size_t)b * 6 + t) * H + h] + b_hh[h];
    if (!first) {
        for (int d = 0; d < H; ++d) acc = fmaf(hp[d], WhhT[(size_t)d * H + h], acc);
    }
    float hn = tanhf(acc);
    if (last) {
        float g = gate[(size_t)b * H + h];
        out[(size_t)b * H + h] = g * hn + (1.f - g) * xp[(size_t)b * 6 * H + h];
    } else {
        hbuf[(size_t)b * H + h] = hn;
    }
}

extern "C" void kernel_launch(void* const* d_in, const int* in_sizes, int n_in,
                              void* d_out, int out_size, void* d_ws, size_t ws_size,
                              hipStream_t stream) {
    const float* query  = (const float*)d_in[0];
    const float* mem    = (const float*)d_in[1];
    const float* coords = (const float*)d_in[2];
    const float* sw     = (const float*)d_in[3];
    const float* W_ih   = (const float*)d_in[4];
    const float* b_ih   = (const float*)d_in[5];
    const float* W_hh   = (const float*)d_in[6];
    const float* b_hh   = (const float*)d_in[7];
    const float* gate_W = (const float*)d_in[8];
    const float* gate_b = (const float*)d_in[9];

    const int H = in_sizes[5];
    const int D = in_sizes[4] / H;
    const int B = in_sizes[0] / D;
    const int M = in_sizes[1] / D;
    const int ntiles = (M + BN - 1) / BN;

    float* W = (float*)d_ws;
    size_t off = 0;
    float* center = W + off; off += 4;
    float* qnT    = W + off; off += (size_t)D * B;
    float* WihT   = W + off; off += (size_t)D * H;
    float* gWT    = W + off; off += (size_t)D * H;
    float* WhhT   = W + off; off += (size_t)H * H;
    float* xp     = W + off; off += (size_t)B * 6 * H;
    float* gate   = W + off; off += (size_t)B * H;
    float* hbuf   = W + off; off += (size_t)B * H;
    float* candV  = W + off; off += (size_t)ntiles * B * TOPK;
    int*   candI  = (int*)(W + off); off += (size_t)ntiles * B * TOPK;
    int*   topk   = (int*)(W + off); off += (size_t)B * TOPK;

    k_center<<<1, 64, 0, stream>>>(sw, H, center);
    k_qnormT<<<B, 128, 0, stream>>>(query, qnT, B, D);
    dim3 tb(32, 8);
    k_transpose<<<dim3((D + 31) / 32, (H + 31) / 32), tb, 0, stream>>>(W_ih, WihT, H, D);
    k_transpose<<<dim3((D + 31) / 32, (H + 31) / 32), tb, 0, stream>>>(gate_W, gWT, H, D);
    k_transpose<<<dim3((H + 31) / 32, (H + 31) / 32), tb, 0, stream>>>(W_hh, WhhT, H, H);
    k_sim_topk<<<dim3(ntiles, B / BM), 256, 0, stream>>>(qnT, mem, coords, center,
                                                         candV, candI, M, B, D);
    k_merge<<<B, 256, 0, stream>>>(candV, candI, ntiles, B, topk);
    k_xproj<<<B, H, 0, stream>>>(query, mem, topk, WihT, gWT, b_ih, gate_b, xp, gate, B, M, D, H);
    for (int t = 0; t <= TOPK; ++t) {
        k_rnn<<<B, H, 0, stream>>>(xp, WhhT, b_hh, hbuf, gate, (float*)d_out,
                                   t, H, (t == 0) ? 1 : 0, (t == TOPK) ? 1 : 0);
    }
}

// Round 2
// 966.339 us; speedup vs baseline: 1.3788x; 1.3788x over previous
//
#include <hip/hip_runtime.h>
#include <math.h>

#define EPSC 1e-8f
#define TOPK 5

typedef _Float16 half8_t __attribute__((ext_vector_type(8)));
typedef float f32x4 __attribute__((ext_vector_type(4)));

__device__ __forceinline__ bool better(float va, int ia, float vb, int ib) {
    return (va > vb) || (va == vb && ia < ib);
}

// ---------------- center = mean(spatial_weights, axis=0) ----------------
__global__ void k_center(const float* __restrict__ sw, int H, float* __restrict__ center) {
    int tid = threadIdx.x;  // 64
    float sx = 0.f, sy = 0.f;
    for (int r = tid; r < H; r += 64) { sx += sw[2 * r]; sy += sw[2 * r + 1]; }
    for (int o = 32; o > 0; o >>= 1) { sx += __shfl_down(sx, o); sy += __shfl_down(sy, o); }
    if (tid == 0) { center[0] = sx / (float)H; center[1] = sy / (float)H; }
}

// ---------------- normalize queries + split to f16 hi/lo in frag-linear layout ----------------
// Aglob layout (f16 elems): plane p (0=hi,1=lo) stride PS=16*KCH*512;
//   within plane: ((qt*KCH)+kc)*512 + (quad*16 + (b&15))*8 + j   where d = kc*32+quad*8+j
__global__ void k_qprep(const float* __restrict__ q, _Float16* __restrict__ Aglob, int B, int D) {
    int b = blockIdx.x;
    int tid = threadIdx.x;  // 128
    const int KCH = D >> 5;
    const int PS = 16 * KCH * 512;
    float ss = 0.f;
    for (int d = tid; d < D; d += 128) { float v = q[(size_t)b * D + d]; ss = fmaf(v, v, ss); }
    for (int o = 32; o > 0; o >>= 1) ss += __shfl_down(ss, o);
    __shared__ float w2[2];
    if ((tid & 63) == 0) w2[tid >> 6] = ss;
    __syncthreads();
    float inv = 1.f / fmaxf(sqrtf(w2[0] + w2[1]), EPSC);
    int qt = b >> 4, nl = b & 15;
    for (int d = tid; d < D; d += 128) {
        float v = q[(size_t)b * D + d] * inv;
        _Float16 hi = (_Float16)v;
        _Float16 lo = (_Float16)(v - (float)hi);
        int kc = d >> 5, r = d & 31, quad = r >> 3, j = r & 7;
        int idx = (qt * KCH + kc) * 512 + (quad * 16 + nl) * 8 + j;
        Aglob[idx] = hi;
        Aglob[PS + idx] = lo;
    }
}

// ---------------- main: split-f16 MFMA sim GEMM + fused norms + per-row top-5 ----------------
// grid: (ceil(M/128)), 256 threads (4 waves). Block: 256 queries x 128 mem rows (2 chunks of 64).
__launch_bounds__(256, 2)
__global__ void k_sim_topk(const _Float16* __restrict__ Aglob, const float* __restrict__ mem,
                           const float* __restrict__ coords, const float* __restrict__ center,
                           float* __restrict__ candV, int* __restrict__ candI,
                           int M, int D) {
    __shared__ __align__(16) char smem[71168];
    _Float16* Ah = (_Float16*)smem;   // [16 qt][512]   16 KB
    _Float16* Al = Ah + 8192;         //                16 KB
    _Float16* Bh = Al + 8192;         // [4 ct][64][8]   4 KB
    _Float16* Bl = Bh + 2048;         //                 4 KB
    float* Cs = (float*)smem;         // epilogue: 4 waves x 64 x 68  (68 KB, overlays A/B)
    float* ssbuf = (float*)(smem + 69632);  // 256
    float* colinv = ssbuf + 256;            // 64
    float* colact = colinv + 64;            // 64

    const int tid = threadIdx.x;
    const int lane = tid & 63, w = tid >> 6;
    const int nB = tid >> 2, qB = tid & 3;  // B staging: mem-row nB (0..63), k-octet qB
    const int KCH = D >> 5;
    const int PS = 16 * KCH * 512;
    const int n0 = blockIdx.x * 128;
    const float cx = center[0], cy = center[1];

    float lv[TOPK]; int li[TOPK];
#pragma unroll
    for (int k = 0; k < TOPK; ++k) { lv[k] = -INFINITY; li[k] = 0x7fffffff; }

    for (int ch = 0; ch < 2; ++ch) {
        const int base = n0 + ch * 64;
        f32x4 acc[4][4];
#pragma unroll
        for (int rt = 0; rt < 4; ++rt)
#pragma unroll
            for (int ct = 0; ct < 4; ++ct) acc[rt][ct] = (f32x4){0.f, 0.f, 0.f, 0.f};
        float ss = 0.f;
        const int brow = base + nB;
        const bool bvalid = brow < M;

        for (int kc = 0; kc < KCH; ++kc) {
            __syncthreads();  // previous iter frag-reads / epilogue done
            // stage A (pure copy of frag-linear f16 planes): 2048 x 16B units
#pragma unroll
            for (int i = 0; i < 8; ++i) {
                int u = tid + i * 256;
                int p = u >> 10, rem = u & 1023, qt = rem >> 6, t = rem & 63;
                *(float4*)(smem + (size_t)u * 16) =
                    *(const float4*)(Aglob + (size_t)p * PS + (qt * KCH + kc) * 512 + t * 8);
            }
            // stage B: load fp32, split to f16 hi/lo, fused sum-of-squares
            {
                half8_t hv, lov;
                float vv[8];
                if (bvalid) {
                    const float* src = mem + (size_t)brow * D + kc * 32 + qB * 8;
                    float4 v0 = *(const float4*)src;
                    float4 v1 = *(const float4*)(src + 4);
                    vv[0] = v0.x; vv[1] = v0.y; vv[2] = v0.z; vv[3] = v0.w;
                    vv[4] = v1.x; vv[5] = v1.y; vv[6] = v1.z; vv[7] = v1.w;
                } else {
#pragma unroll
                    for (int j = 0; j < 8; ++j) vv[j] = 0.f;
                }
#pragma unroll
                for (int j = 0; j < 8; ++j) {
                    ss = fmaf(vv[j], vv[j], ss);
                    _Float16 h = (_Float16)vv[j];
                    hv[j] = h;
                    lov[j] = (_Float16)(vv[j] - (float)h);
                }
                int ct = nB >> 4, nl = nB & 15;
                int off = (ct * 64 + qB * 16 + nl) * 8;
                *(half8_t*)(Bh + off) = hv;
                *(half8_t*)(Bl + off) = lov;
            }
            __syncthreads();
            // fragments + MFMA (3 products per tile: hh, hl, lh)
            half8_t ah[4], al[4], bh[4], bl[4];
#pragma unroll
            for (int rt = 0; rt < 4; ++rt) {
                int qt = w * 4 + rt;
                ah[rt] = *(half8_t*)(Ah + qt * 512 + lane * 8);
                al[rt] = *(half8_t*)(Al + qt * 512 + lane * 8);
            }
#pragma unroll
            for (int ct = 0; ct < 4; ++ct) {
                bh[ct] = *(half8_t*)(Bh + (ct * 64 + lane) * 8);
                bl[ct] = *(half8_t*)(Bl + (ct * 64 + lane) * 8);
            }
#pragma unroll
            for (int rt = 0; rt < 4; ++rt)
#pragma unroll
                for (int ct = 0; ct < 4; ++ct) {
                    acc[rt][ct] = __builtin_amdgcn_mfma_f32_16x16x32_f16(ah[rt], bh[ct], acc[rt][ct], 0, 0, 0);
                    acc[rt][ct] = __builtin_amdgcn_mfma_f32_16x16x32_f16(ah[rt], bl[ct], acc[rt][ct], 0, 0, 0);
                    acc[rt][ct] = __builtin_amdgcn_mfma_f32_16x16x32_f16(al[rt], bh[ct], acc[rt][ct], 0, 0, 0);
                }
        }
        // column stats
        ssbuf[tid] = ss;
        __syncthreads();  // also guarantees all frag-reads done before Cs overlay writes
        if (tid < 64) {
            float s = ssbuf[tid * 4] + ssbuf[tid * 4 + 1] + ssbuf[tid * 4 + 2] + ssbuf[tid * 4 + 3];
            colinv[tid] = 1.f / fmaxf(sqrtf(s), EPSC);
            int m = base + tid;
            float act = -INFINITY;
            if (m < M) {
                float dx = coords[2 * (size_t)m] - cx;
                float dy = coords[2 * (size_t)m + 1] - cy;
                act = 1.f / (1.f + sqrtf(dx * dx + dy * dy));
            }
            colact[tid] = act;
        }
        __syncthreads();
        // epilogue: scale into per-wave LDS C tile (stride 68), then per-row top-5 scan
        float* Cw = Cs + w * (64 * 68);
        const int quad = lane >> 4, c15 = lane & 15;
#pragma unroll
        for (int rt = 0; rt < 4; ++rt)
#pragma unroll
            for (int ct = 0; ct < 4; ++ct) {
                int c = ct * 16 + c15;
                float inv = colinv[c], act = colact[c];
#pragma unroll
                for (int i = 0; i < 4; ++i) {
                    int row = rt * 16 + quad * 4 + i;
                    Cw[row * 68 + c] = fmaf(acc[rt][ct][i], inv, act);
                }
            }
        // same-wave write->read: no barrier needed
        for (int j = 0; j < 64; ++j) {
            int c = (j + lane) & 63;
            float v = Cw[lane * 68 + c];
            int gi = base + c;
            if (better(v, gi, lv[4], li[4])) {
                lv[4] = v; li[4] = gi;
#pragma unroll
                for (int p = 4; p > 0; --p) {
                    if (better(lv[p], li[p], lv[p - 1], li[p - 1])) {
                        float tv = lv[p]; lv[p] = lv[p - 1]; lv[p - 1] = tv;
                        int ti = li[p]; li[p] = li[p - 1]; li[p - 1] = ti;
                    }
                }
            }
        }
        __syncthreads();  // scan done before next chunk restages
    }
    // per-q candidates: q = w*64 + lane
    size_t cb = ((size_t)blockIdx.x * 256 + (w * 64 + lane)) * TOPK;
#pragma unroll
    for (int k = 0; k < TOPK; ++k) { candV[cb + k] = lv[k]; candI[cb + k] = li[k]; }
}

// ---------------- merge per-tile candidates -> global top-5 (sorted desc) ----------------
__global__ void k_merge(const float* __restrict__ candV, const int* __restrict__ candI,
                        int ntiles, int B, int* __restrict__ topk) {
    int b = blockIdx.x;
    int tid = threadIdx.x;  // 256
    float lv[TOPK]; int li[TOPK];
#pragma unroll
    for (int k = 0; k < TOPK; ++k) { lv[k] = -INFINITY; li[k] = 0x7fffffff; }
    for (int t = tid; t < ntiles; t += 256) {
        size_t base = ((size_t)t * B + b) * TOPK;
#pragma unroll
        for (int k = 0; k < TOPK; ++k) {
            float v = candV[base + k]; int gi = candI[base + k];
            if (better(v, gi, lv[4], li[4])) {
                lv[4] = v; li[4] = gi;
#pragma unroll
                for (int p = 4; p > 0; --p) {
                    if (better(lv[p], li[p], lv[p - 1], li[p - 1])) {
                        float tv = lv[p]; lv[p] = lv[p - 1]; lv[p - 1] = tv;
                        int ti = li[p]; li[p] = li[p - 1]; li[p - 1] = ti;
                    }
                }
            }
        }
    }
    __shared__ float sv[256 * TOPK];
    __shared__ int si[256 * TOPK];
#pragma unroll
    for (int k = 0; k < TOPK; ++k) { sv[tid * TOPK + k] = lv[k]; si[tid * TOPK + k] = li[k]; }
    __syncthreads();
    __shared__ float rv[256];
    __shared__ int ri[256], rp[256];
    for (int round = 0; round < TOPK; ++round) {
        float bv = -INFINITY; int bi = 0x7fffffff, bp = -1;
        for (int p = tid; p < 256 * TOPK; p += 256) {
            if (better(sv[p], si[p], bv, bi)) { bv = sv[p]; bi = si[p]; bp = p; }
        }
        rv[tid] = bv; ri[tid] = bi; rp[tid] = bp;
        __syncthreads();
        for (int st = 128; st > 0; st >>= 1) {
            if (tid < st) {
                if (better(rv[tid + st], ri[tid + st], rv[tid], ri[tid])) {
                    rv[tid] = rv[tid + st]; ri[tid] = ri[tid + st]; rp[tid] = rp[tid + st];
                }
            }
            __syncthreads();
        }
        if (tid == 0) {
            topk[b * TOPK + round] = ri[0];
            sv[rp[0]] = -INFINITY;
            si[rp[0]] = 0x7fffffff;
        }
        __syncthreads();
    }
}

// ---------------- gather RNN inputs: INP[b*6+t][D] ----------------
__global__ void k_gather(const float* __restrict__ q, const float* __restrict__ mem,
                         const int* __restrict__ topk, float* __restrict__ inp, int D) {
    int r = blockIdx.x;          // 0..B*6-1
    int b = r / 6, t = r - b * 6;
    int tid = threadIdx.x;       // 96 (D/4)
    const float* src = (t == 0) ? (q + (size_t)b * D)
                                : (mem + (size_t)topk[b * TOPK + (t - 1)] * D);
    *(float4*)&inp[(size_t)r * D + tid * 4] = *(const float4*)&src[tid * 4];
}

// ---------------- generic 64x64-tile fp32 GEMM tail: C = act(A @ W^T + bias [+ addv]) ----------------
// mode 0: dst = v                      (xproj)
// mode 1: dst = sigmoid(v)             (gate)
// mode 2: dst = tanh(v + addv)         (rnn step; skipA=1 => h_prev = 0)
// mode 3: dst = g*tanh(v+addv) + (1-g)*xp0   (final rnn + combine)
__launch_bounds__(256)
__global__ void k_tail_gemm(const float* __restrict__ A, const float* __restrict__ W,
                            const float* __restrict__ bias, const float* __restrict__ addv,
                            int addv_stride, const float* __restrict__ gatep,
                            const float* __restrict__ xp0, int xp0_stride,
                            float* __restrict__ dst, int K, int ldc, int mode, int skipA) {
    __shared__ float As[16 * 68], Ws[16 * 68];
    const int r0 = blockIdx.x * 64, c0 = blockIdx.y * 64;
    const int tid = threadIdx.x;
    float acc[4][4];
#pragma unroll
    for (int i = 0; i < 4; ++i)
#pragma unroll
        for (int j = 0; j < 4; ++j) acc[i][j] = 0.f;
    if (!skipA) {
        const int lr = tid >> 2, lk4 = (tid & 3) * 4;
        for (int k0 = 0; k0 < K; k0 += 16) {
            __syncthreads();
            float4 av = *(const float4*)&A[(size_t)(r0 + lr) * K + k0 + lk4];
            float4 wv = *(const float4*)&W[(size_t)(c0 + lr) * K + k0 + lk4];
            As[(lk4 + 0) * 68 + lr] = av.x; As[(lk4 + 1) * 68 + lr] = av.y;
            As[(lk4 + 2) * 68 + lr] = av.z; As[(lk4 + 3) * 68 + lr] = av.w;
            Ws[(lk4 + 0) * 68 + lr] = wv.x; Ws[(lk4 + 1) * 68 + lr] = wv.y;
            Ws[(lk4 + 2) * 68 + lr] = wv.z; Ws[(lk4 + 3) * 68 + lr] = wv.w;
            __syncthreads();
#pragma unroll
            for (int k = 0; k < 16; ++k) {
                float4 a4 = *(float4*)&As[k * 68 + (tid >> 4) * 4];
                float4 b4 = *(float4*)&Ws[k * 68 + (tid & 15) * 4];
                float a[4] = {a4.x, a4.y, a4.z, a4.w};
                float bb[4] = {b4.x, b4.y, b4.z, b4.w};
#pragma unroll
                for (int i = 0; i < 4; ++i)
#pragma unroll
                    for (int j = 0; j < 4; ++j) acc[i][j] = fmaf(a[i], bb[j], acc[i][j]);
            }
        }
    }
    const int tr = (tid >> 4) * 4, tc = (tid & 15) * 4;
#pragma unroll
    for (int i = 0; i < 4; ++i) {
        int r = r0 + tr + i;
#pragma unroll
        for (int j = 0; j < 4; ++j) {
            int c = c0 + tc + j;
            float v = acc[i][j] + bias[c];
            if (mode >= 2) v += addv[(size_t)r * addv_stride + c];
            float res;
            if (mode == 0) res = v;
            else if (mode == 1) res = 1.f / (1.f + expf(-v));
            else if (mode == 2) res = tanhf(v);
            else {
                float hn = tanhf(v);
                float g = gatep[(size_t)r * ldc + c];
                res = g * hn + (1.f - g) * xp0[(size_t)r * xp0_stride + c];
            }
            dst[(size_t)r * ldc + c] = res;
        }
    }
}

extern "C" void kernel_launch(void* const* d_in, const int* in_sizes, int n_in,
                              void* d_out, int out_size, void* d_ws, size_t ws_size,
                              hipStream_t stream) {
    const float* query  = (const float*)d_in[0];
    const float* mem    = (const float*)d_in[1];
    const float* coords = (const float*)d_in[2];
    const float* sw     = (const float*)d_in[3];
    const float* W_ih   = (const float*)d_in[4];
    const float* b_ih   = (const float*)d_in[5];
    const float* W_hh   = (const float*)d_in[6];
    const float* b_hh   = (const float*)d_in[7];
    const float* gate_W = (const float*)d_in[8];
    const float* gate_b = (const float*)d_in[9];

    const int H = in_sizes[5];           // 512
    const int D = in_sizes[4] / H;       // 384
    const int B = in_sizes[0] / D;       // 256
    const int M = in_sizes[1] / D;       // 200000
    const int KCH = D >> 5;
    const int ntiles = (M + 127) / 128;  // 1563

    float* Wf = (float*)d_ws;
    size_t off = 0;
    _Float16* Aglob = (_Float16*)Wf;     off += (size_t)2 * 16 * KCH * 512 / 2;  // f16 elems /2 = floats
    float* center = Wf + off; off += 4;
    float* candV  = Wf + off; off += (size_t)ntiles * B * TOPK;
    int*   candI  = (int*)(Wf + off); off += (size_t)ntiles * B * TOPK;
    int*   topk   = (int*)(Wf + off); off += B * TOPK;
    float* inp    = Wf + off; off += (size_t)B * 6 * D;
    float* xp     = Wf + off; off += (size_t)B * 6 * H;
    float* gate   = Wf + off; off += (size_t)B * H;
    float* hA     = Wf + off; off += (size_t)B * H;
    float* hB     = Wf + off; off += (size_t)B * H;

    k_center<<<1, 64, 0, stream>>>(sw, H, center);
    k_qprep<<<B, 128, 0, stream>>>(query, Aglob, B, D);
    k_sim_topk<<<ntiles, 256, 0, stream>>>(Aglob, mem, coords, center, candV, candI, M, D);
    k_merge<<<B, 256, 0, stream>>>(candV, candI, ntiles, B, topk);
    k_gather<<<B * 6, D / 4, 0, stream>>>(query, mem, topk, inp, D);
    // xp[b*6+t][H] = INP @ W_ih^T + b_ih
    k_tail_gemm<<<dim3(B * 6 / 64, H / 64), 256, 0, stream>>>(
        inp, W_ih, b_ih, nullptr, 0, nullptr, nullptr, 0, xp, D, H, 0, 0);
    // gate = sigmoid(q @ gate_W^T + gate_b)
    k_tail_gemm<<<dim3(B / 64, H / 64), 256, 0, stream>>>(
        query, gate_W, gate_b, nullptr, 0, nullptr, nullptr, 0, gate, D, H, 1, 0);
    // RNN: h_t = tanh(xp_t + h_{t-1} @ W_hh^T + b_hh); ping-pong hA/hB
    float* hprev = hA; float* hnext = hB;
    for (int t = 0; t <= TOPK; ++t) {
        int first = (t == 0), last = (t == TOPK);
        k_tail_gemm<<<dim3(B / 64, H / 64), 256, 0, stream>>>(
            hprev, W_hh, b_hh, xp + (size_t)t * H, 6 * H, gate, xp, 6 * H,
            last ? (float*)d_out : hnext, H, H, last ? 3 : 2, first);
        float* tmp = hprev; hprev = hnext; hnext = tmp;
    }
}